// Round 1
// baseline (65.605 us; speedup 1.0000x reference)
//
#include <hip/hip_runtime.h>
#include <math.h>

namespace {

constexpr int K_ = 4;
constexpr int T_ = 1024;
constexpr int B_ = 2;
constexpr int D_ = 256;

constexpr int CHUNKS = 16;           // time chunks
constexpr int L_ = T_ / CHUNKS;      // 64 steps per chunk
constexpr int G_ = 16;               // (b,d) sequences per block
constexpr int BLOCK = G_ * CHUNKS;   // 256 threads
constexpr int GRID = (B_ * D_) / G_; // 32 blocks

// Reconstruct Abar, Bbar (bilinear-discretized LegT, N=4, theta=200) exactly
// as the reference does, plus Abar^L for the chunk combine. All inputs are
// compile-time constants -> expect full constant folding at -O3.
__device__ __forceinline__ void compute_consts(float Af[4][4], float Bf[4],
                                               float ALf[4][4]) {
    const double dt = 1.0 / 200.0;
    double P[4], A[4][4];
#pragma unroll
    for (int n = 0; n < 4; ++n) P[n] = sqrt(2.0 * n + 1.0);
#pragma unroll
    for (int n = 0; n < 4; ++n)
#pragma unroll
        for (int k = 0; k < 4; ++k) {
            double s = (n >= k) ? 1.0 : (((k - n) & 1) ? -1.0 : 1.0);
            A[n][k] = -P[n] * P[k] * s;
        }
    // aug = [Q | Mp | B*dt],  Q = I - dt/2*A (diag-dominant),  Mp = I + dt/2*A
    double aug[4][9];
#pragma unroll
    for (int r = 0; r < 4; ++r) {
#pragma unroll
        for (int c = 0; c < 4; ++c) {
            double idc = (r == c) ? 1.0 : 0.0;
            aug[r][c]     = idc - 0.5 * dt * A[r][c];
            aug[r][4 + c] = idc + 0.5 * dt * A[r][c];
        }
        aug[r][8] = P[r] * dt;
    }
    // Gauss-Jordan, no pivoting (Q strongly diag-dominant)
#pragma unroll
    for (int p = 0; p < 4; ++p) {
        double pinv = 1.0 / aug[p][p];
#pragma unroll
        for (int c = 0; c < 9; ++c) aug[p][c] *= pinv;
#pragma unroll
        for (int r = 0; r < 4; ++r) {
            if (r == p) continue;
            double f = aug[r][p];
#pragma unroll
            for (int c = 0; c < 9; ++c) aug[r][c] -= f * aug[p][c];
        }
    }
#pragma unroll
    for (int r = 0; r < 4; ++r) {
#pragma unroll
        for (int c = 0; c < 4; ++c) Af[r][c] = (float)aug[r][4 + c];
        Bf[r] = (float)aug[r][8];
    }
    // Abar^L via log2(L)=6 squarings (float is plenty: error ~1e-6 << 6.4e-3)
    float X[4][4];
#pragma unroll
    for (int r = 0; r < 4; ++r)
#pragma unroll
        for (int c = 0; c < 4; ++c) X[r][c] = Af[r][c];
#pragma unroll
    for (int s = 0; s < 6; ++s) {
        float Y[4][4];
#pragma unroll
        for (int r = 0; r < 4; ++r)
#pragma unroll
            for (int c = 0; c < 4; ++c) {
                float acc = 0.f;
#pragma unroll
                for (int k = 0; k < 4; ++k) acc = fmaf(X[r][k], X[k][c], acc);
                Y[r][c] = acc;
            }
#pragma unroll
        for (int r = 0; r < 4; ++r)
#pragma unroll
            for (int c = 0; c < 4; ++c) X[r][c] = Y[r][c];
    }
#pragma unroll
    for (int r = 0; r < 4; ++r)
#pragma unroll
        for (int c = 0; c < 4; ++c) ALf[r][c] = X[r][c];
}

__global__ __launch_bounds__(BLOCK) void hippo_scan(
    const float* __restrict__ h, const float* __restrict__ M,
    float* __restrict__ out)
{
    const int tid   = threadIdx.x;
    const int lane  = tid & (G_ - 1);  // d-lane within block: 0..15
    const int chunk = tid >> 4;        // time chunk: 0..15
    const int g = blockIdx.x * G_ + lane;   // sequence id 0..511
    const int b = g >> 8;                   // g / D_
    const int d = g & (D_ - 1);

    const float* hp = h + (size_t)(b * T_ + chunk * L_) * D_ + d;

    // ---- Phase 1: chunk-local end state y_c = sum_i M[L-1-i] * h[cL+i] ----
    float y0 = 0.f, y1 = 0.f, y2 = 0.f, y3 = 0.f;
#pragma unroll 8
    for (int i = 0; i < L_; ++i) {
        float hv = hp[i * D_];
        const float* mr = M + (L_ - 1 - i) * K_;  // same row for all lanes
        y0 = fmaf(mr[0], hv, y0);
        y1 = fmaf(mr[1], hv, y1);
        y2 = fmaf(mr[2], hv, y2);
        y3 = fmaf(mr[3], hv, y3);
    }

    __shared__ float yst[CHUNKS][G_][K_];
    __shared__ float ini[CHUNKS][G_][K_];
    yst[chunk][lane][0] = y0; yst[chunk][lane][1] = y1;
    yst[chunk][lane][2] = y2; yst[chunk][lane][3] = y3;

    float Af[4][4], Bf[4], ALf[4][4];
    compute_consts(Af, Bf, ALf);   // expected to constant-fold

    __syncthreads();

    // ---- Combine: init[c] = y_{c-1} + Abar^L * init[c-1] (16 lanes) ----
    if (tid < G_) {
        float x0 = 0.f, x1 = 0.f, x2 = 0.f, x3 = 0.f;
#pragma unroll
        for (int c = 0; c < CHUNKS; ++c) {
            ini[c][tid][0] = x0; ini[c][tid][1] = x1;
            ini[c][tid][2] = x2; ini[c][tid][3] = x3;
            float e0 = yst[c][tid][0], e1 = yst[c][tid][1];
            float e2 = yst[c][tid][2], e3 = yst[c][tid][3];
            float n0 = fmaf(ALf[0][0], x0, fmaf(ALf[0][1], x1, fmaf(ALf[0][2], x2, fmaf(ALf[0][3], x3, e0))));
            float n1 = fmaf(ALf[1][0], x0, fmaf(ALf[1][1], x1, fmaf(ALf[1][2], x2, fmaf(ALf[1][3], x3, e1))));
            float n2 = fmaf(ALf[2][0], x0, fmaf(ALf[2][1], x1, fmaf(ALf[2][2], x2, fmaf(ALf[2][3], x3, e2))));
            float n3 = fmaf(ALf[3][0], x0, fmaf(ALf[3][1], x1, fmaf(ALf[3][2], x2, fmaf(ALf[3][3], x3, e3))));
            x0 = n0; x1 = n1; x2 = n2; x3 = n3;
        }
    }
    __syncthreads();

    // ---- Phase 2: recurrence with proper init; every state is an output ----
    float x0 = ini[chunk][lane][0], x1 = ini[chunk][lane][1];
    float x2 = ini[chunk][lane][2], x3 = ini[chunk][lane][3];

    float* op = out + (size_t)(b * T_ + chunk * L_) * K_ * D_ + d;
#pragma unroll 4
    for (int i = 0; i < L_; ++i) {
        float hv = hp[i * D_];
        float n0 = fmaf(Af[0][0], x0, fmaf(Af[0][1], x1, fmaf(Af[0][2], x2, fmaf(Af[0][3], x3, Bf[0] * hv))));
        float n1 = fmaf(Af[1][0], x0, fmaf(Af[1][1], x1, fmaf(Af[1][2], x2, fmaf(Af[1][3], x3, Bf[1] * hv))));
        float n2 = fmaf(Af[2][0], x0, fmaf(Af[2][1], x1, fmaf(Af[2][2], x2, fmaf(Af[2][3], x3, Bf[2] * hv))));
        float n3 = fmaf(Af[3][0], x0, fmaf(Af[3][1], x1, fmaf(Af[3][2], x2, fmaf(Af[3][3], x3, Bf[3] * hv))));
        x0 = n0; x1 = n1; x2 = n2; x3 = n3;
        op[0 * D_] = x0; op[1 * D_] = x1; op[2 * D_] = x2; op[3 * D_] = x3;
        op += K_ * D_;
    }
}

} // namespace

extern "C" void kernel_launch(void* const* d_in, const int* in_sizes, int n_in,
                              void* d_out, int out_size, void* d_ws, size_t ws_size,
                              hipStream_t stream) {
    const float* h = (const float*)d_in[0];   // (B, T, D) fp32
    const float* M = (const float*)d_in[1];   // (T, K)    fp32
    float* out = (float*)d_out;               // (B, T, K, D) fp32
    hippo_scan<<<GRID, BLOCK, 0, stream>>>(h, M, out);
}

// Round 2
// 63.684 us; speedup vs baseline: 1.0302x; 1.0302x over previous
//
#include <hip/hip_runtime.h>
#include <math.h>

namespace {

constexpr int K_ = 4;
constexpr int T_ = 1024;
constexpr int B_ = 2;
constexpr int D_ = 256;
constexpr int NSEQ = B_ * D_;        // 512 independent (b,d) sequences

constexpr int CH = 128;              // fine time chunks
constexpr int L_ = T_ / CH;          // 8 steps per chunk
constexpr int LOG_CH = 7;

// ---------------------------------------------------------------------------
// Compile-time-foldable constants: Abar, Bbar (bilinear LegT, N=4, theta=200)
// exactly as the reference builds them, plus AP[s] = Abar^(L*2^s), s=0..6.
// ---------------------------------------------------------------------------
__device__ __forceinline__ void base_consts(float Af[4][4], float Bf[4]) {
    const double dt = 1.0 / 200.0;
    double P[4], A[4][4];
#pragma unroll
    for (int n = 0; n < 4; ++n) P[n] = sqrt(2.0 * n + 1.0);
#pragma unroll
    for (int n = 0; n < 4; ++n)
#pragma unroll
        for (int k = 0; k < 4; ++k) {
            double s = (n >= k) ? 1.0 : (((k - n) & 1) ? -1.0 : 1.0);
            A[n][k] = -P[n] * P[k] * s;
        }
    double aug[4][9];
#pragma unroll
    for (int r = 0; r < 4; ++r) {
#pragma unroll
        for (int c = 0; c < 4; ++c) {
            double idc = (r == c) ? 1.0 : 0.0;
            aug[r][c]     = idc - 0.5 * dt * A[r][c];
            aug[r][4 + c] = idc + 0.5 * dt * A[r][c];
        }
        aug[r][8] = P[r] * dt;
    }
#pragma unroll
    for (int p = 0; p < 4; ++p) {
        double pinv = 1.0 / aug[p][p];
#pragma unroll
        for (int c = 0; c < 9; ++c) aug[p][c] *= pinv;
#pragma unroll
        for (int r = 0; r < 4; ++r) {
            if (r == p) continue;
            double f = aug[r][p];
#pragma unroll
            for (int c = 0; c < 9; ++c) aug[r][c] -= f * aug[p][c];
        }
    }
#pragma unroll
    for (int r = 0; r < 4; ++r) {
#pragma unroll
        for (int c = 0; c < 4; ++c) Af[r][c] = (float)aug[r][4 + c];
        Bf[r] = (float)aug[r][8];
    }
}

__device__ __forceinline__ void matsq(const float X[4][4], float Y[4][4]) {
#pragma unroll
    for (int r = 0; r < 4; ++r)
#pragma unroll
        for (int c = 0; c < 4; ++c) {
            float acc = 0.f;
#pragma unroll
            for (int k = 0; k < 4; ++k) acc = fmaf(X[r][k], X[k][c], acc);
            Y[r][c] = acc;
        }
}

// AP[s] = Abar^(8 * 2^s), s = 0..LOG_CH-1
__device__ __forceinline__ void scan_consts(float AP[LOG_CH][4][4]) {
    float Af[4][4], Bf[4];
    base_consts(Af, Bf);
    float X[4][4], Y[4][4];
    matsq(Af, X);      // A^2
    matsq(X, Y);       // A^4
    matsq(Y, X);       // A^8
#pragma unroll
    for (int s = 0; s < LOG_CH; ++s) {
#pragma unroll
        for (int r = 0; r < 4; ++r)
#pragma unroll
            for (int c = 0; c < 4; ++c) AP[s][r][c] = X[r][c];
        matsq(X, Y);
#pragma unroll
        for (int r = 0; r < 4; ++r)
#pragma unroll
            for (int c = 0; c < 4; ++c) X[r][c] = Y[r][c];
    }
}

// ---------------------------------------------------------------------------
// k1a: chunk-local end states  y[c][seq] = sum_{i<L} M[L-1-i] * h[c*L+i]
// block = 4 chunks x 64 d-lanes (wave = 64 consecutive d -> 256B coalesced)
// grid  = (NSEQ/64) * (CH/4) = 8 * 32 = 256
// ---------------------------------------------------------------------------
__global__ __launch_bounds__(256) void k1a_chunk_states(
    const float* __restrict__ h, const float* __restrict__ M,
    float* __restrict__ ws_y)
{
    const int dlane = threadIdx.x & 63;
    const int csub  = threadIdx.x >> 6;       // 0..3
    const int sg    = blockIdx.x & 7;         // seq group (64 seqs)
    const int cg    = blockIdx.x >> 3;        // chunk group (4 chunks)
    const int seq = sg * 64 + dlane;
    const int b = seq >> 8, d = seq & (D_ - 1);
    const int c = cg * 4 + csub;

    const float* hp = h + ((size_t)(b * T_ + c * L_)) * D_ + d;
    float y0 = 0.f, y1 = 0.f, y2 = 0.f, y3 = 0.f;
#pragma unroll
    for (int i = 0; i < L_; ++i) {
        float hv = hp[i * D_];
        const float* mr = M + (L_ - 1 - i) * K_;
        y0 = fmaf(mr[0], hv, y0);
        y1 = fmaf(mr[1], hv, y1);
        y2 = fmaf(mr[2], hv, y2);
        y3 = fmaf(mr[3], hv, y3);
    }
    float4* wp = (float4*)ws_y + (size_t)c * NSEQ + seq;  // [c][seq][4]
    *wp = make_float4(y0, y1, y2, y3);
}

// ---------------------------------------------------------------------------
// k1b: Kogge-Stone scan across 128 chunks per sequence (constant matrices).
// block = 128 chunks x 2 seqs; grid = NSEQ/2 = 256.
// Writes EXCLUSIVE prefix (chunk-start state) to ws_init[c][seq].
// ---------------------------------------------------------------------------
__global__ __launch_bounds__(256) void k1b_scan(
    const float* __restrict__ ws_y, float* __restrict__ ws_init)
{
    const int sp = threadIdx.x & 1;
    const int c  = threadIdx.x >> 1;          // 0..127
    const int seq = blockIdx.x * 2 + sp;

    float AP[LOG_CH][4][4];
    scan_consts(AP);

    float4 v = ((const float4*)ws_y)[(size_t)c * NSEQ + seq];

    __shared__ float4 lds[CH * 2];
#pragma unroll
    for (int s = 0; s < LOG_CH; ++s) {
        const int off = 1 << s;
        lds[threadIdx.x] = v;
        __syncthreads();
        if (c >= off) {
            float4 p = lds[threadIdx.x - off * 2];
            v.x = fmaf(AP[s][0][0], p.x, fmaf(AP[s][0][1], p.y, fmaf(AP[s][0][2], p.z, fmaf(AP[s][0][3], p.w, v.x))));
            v.y = fmaf(AP[s][1][0], p.x, fmaf(AP[s][1][1], p.y, fmaf(AP[s][1][2], p.z, fmaf(AP[s][1][3], p.w, v.y))));
            v.z = fmaf(AP[s][2][0], p.x, fmaf(AP[s][2][1], p.y, fmaf(AP[s][2][2], p.z, fmaf(AP[s][2][3], p.w, v.z))));
            v.w = fmaf(AP[s][3][0], p.x, fmaf(AP[s][3][1], p.y, fmaf(AP[s][3][2], p.z, fmaf(AP[s][3][3], p.w, v.w))));
        }
        __syncthreads();
    }
    // v = inclusive state after chunk c; init[c+1] = v, init[0] = 0
    float4* ip = (float4*)ws_init;
    if (c < CH - 1) ip[(size_t)(c + 1) * NSEQ + seq] = v;
    if (c == 0)     ip[seq] = make_float4(0.f, 0.f, 0.f, 0.f);
}

// ---------------------------------------------------------------------------
// k2: per-chunk recurrence with proper init; all loads/stores 1KiB-coalesced.
// block = 256 threads (one per d); grid = B * CH = 256 blocks.
// ---------------------------------------------------------------------------
__global__ __launch_bounds__(256) void k2_emit(
    const float* __restrict__ h, const float* __restrict__ ws_init,
    float* __restrict__ out)
{
    const int d = threadIdx.x;
    const int c = blockIdx.x & (CH - 1);
    const int b = blockIdx.x >> LOG_CH;

    float Af[4][4], Bf[4];
    base_consts(Af, Bf);

    float4 xi = ((const float4*)ws_init)[(size_t)c * NSEQ + b * D_ + d];
    float x0 = xi.x, x1 = xi.y, x2 = xi.z, x3 = xi.w;

    const float* hp = h + ((size_t)(b * T_ + c * L_)) * D_ + d;
    float* op = out + ((size_t)(b * T_ + c * L_)) * K_ * D_ + d;
#pragma unroll
    for (int i = 0; i < L_; ++i) {
        float hv = hp[i * D_];
        float n0 = fmaf(Af[0][0], x0, fmaf(Af[0][1], x1, fmaf(Af[0][2], x2, fmaf(Af[0][3], x3, Bf[0] * hv))));
        float n1 = fmaf(Af[1][0], x0, fmaf(Af[1][1], x1, fmaf(Af[1][2], x2, fmaf(Af[1][3], x3, Bf[1] * hv))));
        float n2 = fmaf(Af[2][0], x0, fmaf(Af[2][1], x1, fmaf(Af[2][2], x2, fmaf(Af[2][3], x3, Bf[2] * hv))));
        float n3 = fmaf(Af[3][0], x0, fmaf(Af[3][1], x1, fmaf(Af[3][2], x2, fmaf(Af[3][3], x3, Bf[3] * hv))));
        x0 = n0; x1 = n1; x2 = n2; x3 = n3;
        op[0 * D_] = x0; op[1 * D_] = x1; op[2 * D_] = x2; op[3 * D_] = x3;
        op += K_ * D_;
    }
}

} // namespace

extern "C" void kernel_launch(void* const* d_in, const int* in_sizes, int n_in,
                              void* d_out, int out_size, void* d_ws, size_t ws_size,
                              hipStream_t stream) {
    const float* h = (const float*)d_in[0];   // (B, T, D) fp32
    const float* M = (const float*)d_in[1];   // (T, K)    fp32
    float* out = (float*)d_out;               // (B, T, K, D) fp32

    // ws layout: y[CH][NSEQ][4] then init[CH][NSEQ][4]  (1 MiB each)
    float* ws_y    = (float*)d_ws;
    float* ws_init = ws_y + (size_t)CH * NSEQ * K_;

    k1a_chunk_states<<<(NSEQ / 64) * (CH / 4), 256, 0, stream>>>(h, M, ws_y);
    k1b_scan<<<NSEQ / 2, 256, 0, stream>>>(ws_y, ws_init);
    k2_emit<<<B_ * CH, 256, 0, stream>>>(h, ws_init, out);
}